// Round 20
// baseline (220.510 us; speedup 1.0000x reference)
//
#include <hip/hip_runtime.h>
#include <hip/hip_bf16.h>
#include <math.h>

// Graph transformer: 2x TransformerConv (PyG-style).
// GEMMs in bf16 MFMA (dbuf LDS + reg prefetch) with fragment-major weight
// panel; bf16 table [N][256] = q|k|v|skip. Layer-1 GEMM fused with edge
// histogram. Attention fused per-dst-node over CSR, group-parallel online
// softmax, 2 edges/group/iter with index prefetch. 3-kernel scan CSR.

typedef __attribute__((ext_vector_type(4))) float f32x4;
typedef __attribute__((ext_vector_type(8))) short bf16x8;
typedef __attribute__((ext_vector_type(8))) unsigned short u16x8;

__device__ inline unsigned short f2bf(float f) {
    union { float f; unsigned u; } v; v.f = f;
    unsigned r = (v.u + 0x7fffu + ((v.u >> 16) & 1u)) >> 16;
    return (unsigned short)r;
}
__device__ inline float bf2f(unsigned short u) {
    union { unsigned u; float f; } v; v.u = ((unsigned)u) << 16; return v.f;
}

#define NEGBIG (-1e30f)

// ---------------- fused setup: both weight panels + deg zero ----------------
__device__ inline void prep_panel(int i, int K,
                                  const float* __restrict__ W0, const float* __restrict__ b0,
                                  const float* __restrict__ W1, const float* __restrict__ b1,
                                  const float* __restrict__ W2, const float* __restrict__ b2,
                                  const float* __restrict__ W3, const float* __restrict__ b3,
                                  unsigned short* __restrict__ Btp, float* __restrict__ bias) {
    int tot = 4 * K * 64;
    if (i < tot) {
        int j    = i & 7;
        int lane = (i >> 3) & 63;
        int ni   = (i >> 9) & 3;
        int kk   = (i >> 11) & 1;
        int w    = (i >> 12) & 3;
        int ks   = i >> 14;
        int ncol = ni * 16 + (lane & 15);
        int k    = ks * 64 + kk * 32 + ((lane >> 4) << 3) + j;
        const float* W = (w == 0) ? W0 : (w == 1) ? W1 : (w == 2) ? W2 : W3;
        Btp[i] = f2bf(W[k * 64 + ncol]);
    }
    if (i < 256) {
        int which = i >> 6;
        const float* b = (which == 0) ? b0 : (which == 1) ? b1 : (which == 2) ? b2 : b3;
        bias[i] = b[i & 63];
    }
}

__global__ void setup_all(const float* __restrict__ Wq1, const float* __restrict__ bq1,
                          const float* __restrict__ Wk1, const float* __restrict__ bk1,
                          const float* __restrict__ Wv1, const float* __restrict__ bv1,
                          const float* __restrict__ Ws1, const float* __restrict__ bs1,
                          const float* __restrict__ Wq2, const float* __restrict__ bq2,
                          const float* __restrict__ Wk2, const float* __restrict__ bk2,
                          const float* __restrict__ Wv2, const float* __restrict__ bv2,
                          const float* __restrict__ Ws2, const float* __restrict__ bs2,
                          unsigned short* __restrict__ bt1, float* __restrict__ bias1,
                          unsigned short* __restrict__ bt2, float* __restrict__ bias2,
                          int* __restrict__ deg, int N) {
    const int b = blockIdx.x;
    const int tid = threadIdx.x;
    if (b < 512) {
        prep_panel(b * 256 + tid, 512, Wq1, bq1, Wk1, bk1, Wv1, bv1, Ws1, bs1, bt1, bias1);
    } else if (b < 512 + 64) {
        prep_panel((b - 512) * 256 + tid, 64, Wq2, bq2, Wk2, bk2, Wv2, bv2, Ws2, bs2, bt2, bias2);
    } else {
        int i = (b - 576) * 256 + tid;
        if (i < N) deg[i] = 0;
    }
}

// ---------------- MFMA GEMM body (device fn): dbuf LDS + reg prefetch ----------------
template<int KSTEPS, bool ABF16>
__device__ void gemm_body(const void* __restrict__ Av, int M,
                          const unsigned short* __restrict__ Bt,
                          const float* __restrict__ bias,
                          unsigned short* __restrict__ outbf, int blk) {
    constexpr int K = KSTEPS * 64;
    __shared__ unsigned short As[2][64][72];
    const int tid = threadIdx.x;
    const int lane = tid & 63;
    const int w = tid >> 6;
    const int node0 = blk * 64;
    const int r16 = lane & 15, g = lane >> 4;

    f32x4 acc[4][4] = {};

    const int srow = tid >> 2;
    const int sc0 = (tid & 3) * 16;
    const int node = node0 + srow;
    const bool nvalid = node < M;

    float4 f0, f1, f2, f3;
    u16x8 a0, a1;

#define ISSUE_LOAD(KS)                                                                     \
    do {                                                                                   \
        if (ABF16) {                                                                       \
            a0 = (u16x8){}; a1 = (u16x8){};                                                \
            if (nvalid) {                                                                  \
                const u16x8* p = (const u16x8*)((const unsigned short*)Av +                \
                                  (size_t)node * K + (KS) * 64 + sc0);                     \
                a0 = p[0]; a1 = p[1];                                                      \
            }                                                                              \
        } else {                                                                           \
            f0 = make_float4(0.f, 0.f, 0.f, 0.f); f1 = f0; f2 = f0; f3 = f0;               \
            if (nvalid) {                                                                  \
                const float4* p = (const float4*)((const float*)Av +                       \
                                   (size_t)node * K + (KS) * 64 + sc0);                    \
                f0 = p[0]; f1 = p[1]; f2 = p[2]; f3 = p[3];                                \
            }                                                                              \
        }                                                                                  \
    } while (0)

#define WRITE_LDS(BUF)                                                                     \
    do {                                                                                   \
        unsigned short t[16];                                                              \
        if (ABF16) {                                                                       \
            _Pragma("unroll")                                                              \
            for (int j = 0; j < 8; ++j) { t[j] = a0[j]; t[8 + j] = a1[j]; }                \
        } else {                                                                           \
            t[0] = f2bf(f0.x); t[1] = f2bf(f0.y); t[2] = f2bf(f0.z); t[3] = f2bf(f0.w);    \
            t[4] = f2bf(f1.x); t[5] = f2bf(f1.y); t[6] = f2bf(f1.z); t[7] = f2bf(f1.w);    \
            t[8] = f2bf(f2.x); t[9] = f2bf(f2.y); t[10] = f2bf(f2.z); t[11] = f2bf(f2.w);  \
            t[12] = f2bf(f3.x); t[13] = f2bf(f3.y); t[14] = f2bf(f3.z); t[15] = f2bf(f3.w);\
        }                                                                                  \
        u16x8 w0, w1;                                                                      \
        _Pragma("unroll")                                                                  \
        for (int j = 0; j < 8; ++j) { w0[j] = t[j]; w1[j] = t[8 + j]; }                    \
        *(u16x8*)&As[BUF][srow][sc0] = w0;                                                 \
        *(u16x8*)&As[BUF][srow][sc0 + 8] = w1;                                             \
    } while (0)

    ISSUE_LOAD(0);
    WRITE_LDS(0);
    __syncthreads();

#pragma unroll
    for (int ks = 0; ks < KSTEPS; ++ks) {
        bf16x8 bfr[8];
#pragma unroll
        for (int kk = 0; kk < 2; ++kk)
#pragma unroll
            for (int ni = 0; ni < 4; ++ni)
                bfr[kk * 4 + ni] = *(const bf16x8*)&Bt[
                    ((size_t)(((ks * 4 + w) * 2 + kk) * 4 + ni) << 9) + (lane << 3)];
        if (ks + 1 < KSTEPS) ISSUE_LOAD(ks + 1);

#pragma unroll
        for (int kk = 0; kk < 2; ++kk) {
            bf16x8 afr[4];
#pragma unroll
            for (int mi = 0; mi < 4; ++mi)
                afr[mi] = *(const bf16x8*)&As[ks & 1][mi * 16 + r16][kk * 32 + g * 8];
#pragma unroll
            for (int ni = 0; ni < 4; ++ni)
#pragma unroll
                for (int mi = 0; mi < 4; ++mi)
                    acc[mi][ni] = __builtin_amdgcn_mfma_f32_16x16x32_bf16(
                        afr[mi], bfr[kk * 4 + ni], acc[mi][ni], 0, 0, 0);
        }

        if (ks + 1 < KSTEPS) WRITE_LDS((ks + 1) & 1);
        __syncthreads();
    }
#undef ISSUE_LOAD
#undef WRITE_LDS

#pragma unroll
    for (int mi = 0; mi < 4; ++mi) {
#pragma unroll
        for (int r = 0; r < 4; ++r) {
            int row = node0 + mi * 16 + g * 4 + r;
            if (row < M) {
                size_t o = (size_t)row * 256 + w * 64;
#pragma unroll
                for (int ni = 0; ni < 4; ++ni)
                    outbf[o + ni * 16 + r16] =
                        f2bf(acc[mi][ni][r] + bias[w * 64 + ni * 16 + r16]);
            }
        }
    }
}

// standalone GEMM kernel (layer 2)
template<int KSTEPS, bool ABF16>
__global__ __launch_bounds__(256) void gemm_mfma(const void* __restrict__ Av, int M,
                                                 const unsigned short* __restrict__ Bt,
                                                 const float* __restrict__ bias,
                                                 unsigned short* __restrict__ outbf) {
    gemm_body<KSTEPS, ABF16>(Av, M, Bt, bias, outbf, blockIdx.x);
}

// layer-1 GEMM fused with edge histogram (independent work, one launch)
__global__ __launch_bounds__(256) void gemm1_hist(const float* __restrict__ x, int M,
                                                  const unsigned short* __restrict__ Bt,
                                                  const float* __restrict__ bias,
                                                  unsigned short* __restrict__ outbf,
                                                  const int* __restrict__ dst, int E, int N,
                                                  int* __restrict__ deg, int gB) {
    if (blockIdx.x < gB) {
        gemm_body<8, false>(x, M, Bt, bias, outbf, blockIdx.x);
    } else {
        int base = ((blockIdx.x - gB) * 256 + threadIdx.x) * 4;
        if (base + 3 < E) {
            int4 d4 = *(const int4*)&dst[base];
            if ((unsigned)d4.x < (unsigned)N) atomicAdd(&deg[d4.x], 1);
            if ((unsigned)d4.y < (unsigned)N) atomicAdd(&deg[d4.y], 1);
            if ((unsigned)d4.z < (unsigned)N) atomicAdd(&deg[d4.z], 1);
            if ((unsigned)d4.w < (unsigned)N) atomicAdd(&deg[d4.w], 1);
        } else {
            for (int i = 0; i < 4; ++i) {
                int e = base + i;
                if (e < E) {
                    int d = dst[e];
                    if ((unsigned)d < (unsigned)N) atomicAdd(&deg[d], 1);
                }
            }
        }
    }
}

// ---------------- CSR scan ----------------
__global__ __launch_bounds__(256) void scan_blk_k(const int* __restrict__ deg, int N,
                                                  int* __restrict__ rowptr,
                                                  int* __restrict__ blk_sums) {
    __shared__ int wsum[4];
    const int t = threadIdx.x;
    const int base = blockIdx.x * 1024 + t * 4;
    int d0 = 0, d1 = 0, d2 = 0, d3 = 0;
    if (base + 3 < N) {
        int4 v = *(const int4*)&deg[base];
        d0 = v.x; d1 = v.y; d2 = v.z; d3 = v.w;
    } else {
        if (base < N)     d0 = deg[base];
        if (base + 1 < N) d1 = deg[base + 1];
        if (base + 2 < N) d2 = deg[base + 2];
    }
    int s = d0 + d1 + d2 + d3;
    int incl = s;
    const int lane = t & 63, w = t >> 6;
#pragma unroll
    for (int off = 1; off < 64; off <<= 1) {
        int v = __shfl_up(incl, off, 64);
        if (lane >= off) incl += v;
    }
    if (lane == 63) wsum[w] = incl;
    __syncthreads();
    int woff = 0;
    if (w > 0) woff += wsum[0];
    if (w > 1) woff += wsum[1];
    if (w > 2) woff += wsum[2];
    int excl = woff + incl - s;
    if (base < N)     rowptr[base]     = excl;
    if (base + 1 < N) rowptr[base + 1] = excl + d0;
    if (base + 2 < N) rowptr[base + 2] = excl + d0 + d1;
    if (base + 3 < N) rowptr[base + 3] = excl + d0 + d1 + d2;
    if (t == 255) blk_sums[blockIdx.x] = woff + incl;
}

__global__ __launch_bounds__(64) void scan_top_k(const int* __restrict__ blk_sums,
                                                 int* __restrict__ blk_off, int nblk,
                                                 int* __restrict__ rowptrN) {
    const int lane = threadIdx.x;
    int carry = 0;
    for (int b = 0; b < nblk; b += 64) {
        int idx = b + lane;
        int v = (idx < nblk) ? blk_sums[idx] : 0;
        int incl = v;
#pragma unroll
        for (int off = 1; off < 64; off <<= 1) {
            int u = __shfl_up(incl, off, 64);
            if (lane >= off) incl += u;
        }
        if (idx < nblk) blk_off[idx] = carry + incl - v;
        carry += __shfl(incl, 63, 64);
    }
    if (lane == 0) *rowptrN = carry;
}

__global__ __launch_bounds__(256) void scan_add_k(int* __restrict__ rowptr,
                                                  int* __restrict__ rowptr2,
                                                  const int* __restrict__ blk_off, int N) {
    const int base = blockIdx.x * 1024 + threadIdx.x * 4;
    const int off = blk_off[blockIdx.x];
    if (base + 3 < N) {
        int4 v = *(int4*)&rowptr[base];
        v.x += off; v.y += off; v.z += off; v.w += off;
        *(int4*)&rowptr[base] = v;
        *(int4*)&rowptr2[base] = v;
    } else {
        for (int i = 0; i < 4; ++i)
            if (base + i < N) {
                int v = rowptr[base + i] + off;
                rowptr[base + i] = v;
                rowptr2[base + i] = v;
            }
    }
}

__global__ void scatter_edges(const int* __restrict__ src, const int* __restrict__ dst,
                              int E, int N,
                              int* __restrict__ rowptr2, int* __restrict__ csr_src) {
    int e = blockIdx.x * 256 + threadIdx.x;
    if (e >= E) return;
    int d = dst[e];
    if ((unsigned)d >= (unsigned)N) return;
    int slot = atomicAdd(&rowptr2[d], 1);
    if ((unsigned)slot < (unsigned)E) csr_src[slot] = src[e];
}

// ---------------- fused attention layer 1 (H=8, C=8) ----------------
// One wave per node; 8 groups x 8 lanes; lane owns head h = lane&7.
// 2 edges per group per iteration; NEXT iteration's indices prefetched.
__global__ __launch_bounds__(256) void attn1(const unsigned short* __restrict__ qbf,
                                             const int* __restrict__ rowptr,
                                             const int* __restrict__ csr_src,
                                             unsigned short* __restrict__ h1bf, int N) {
    int node = blockIdx.x * 4 + (threadIdx.x >> 6);
    if (node >= N) return;
    const int lane = threadIdx.x & 63;
    const int g = lane >> 3, h = lane & 7;

    float q[8];
    {
        u16x8 qv = *(const u16x8*)(qbf + (size_t)node * 256 + h * 8);
#pragma unroll
        for (int i = 0; i < 8; ++i) q[i] = bf2f(qv[i]);
    }

    const float SC = 1.44269504f * 0.35355339059327373f;   // log2(e)/sqrt(8)
    float m = NEGBIG, l = 0.f;
    float a[8] = {};

    const int beg = rowptr[node], end = rowptr[node + 1];
    const int nt = (end - beg + 15) >> 4;

    // prefetch indices for t = 0
    int ni0 = beg + g, ni1 = ni0 + 8;
    bool nv0 = ni0 < end, nv1 = ni1 < end;
    int ns0 = csr_src[nv0 ? ni0 : beg];
    int ns1 = csr_src[nv1 ? ni1 : beg];

    for (int t = 0; t < nt; ++t) {
        bool v0 = nv0, v1 = nv1;
        int s0 = ((unsigned)ns0 < (unsigned)N) ? ns0 : 0;
        int s1 = ((unsigned)ns1 < (unsigned)N) ? ns1 : 0;
        // prefetch indices for t+1 (clamped; overlaps with gathers below)
        int i0n = beg + (t + 1) * 16 + g, i1n = i0n + 8;
        nv0 = i0n < end; nv1 = i1n < end;
        ns0 = csr_src[nv0 ? i0n : beg];
        ns1 = csr_src[nv1 ? i1n : beg];

        const unsigned short* kb0 = qbf + (size_t)s0 * 256 + 64 + h * 8;
        const unsigned short* kb1 = qbf + (size_t)s1 * 256 + 64 + h * 8;
        u16x8 ku0 = *(const u16x8*)kb0;
        u16x8 vu0 = *(const u16x8*)(kb0 + 64);
        u16x8 ku1 = *(const u16x8*)kb1;
        u16x8 vu1 = *(const u16x8*)(kb1 + 64);
        float p0 = 0.f, p1 = 0.f;
#pragma unroll
        for (int i = 0; i < 8; ++i) { p0 += q[i] * bf2f(ku0[i]); p1 += q[i] * bf2f(ku1[i]); }
        float x0 = v0 ? (p0 * SC) : NEGBIG;
        float x1 = v1 ? (p1 * SC) : NEGBIG;
        float mnew = fmaxf(m, fmaxf(x0, x1));
        float corr = exp2f(m - mnew);
        float w0 = v0 ? exp2f(x0 - mnew) : 0.f;
        float w1 = v1 ? exp2f(x1 - mnew) : 0.f;
        l = l * corr + w0 + w1;
#pragma unroll
        for (int i = 0; i < 8; ++i)
            a[i] = a[i] * corr + w0 * bf2f(vu0[i]) + w1 * bf2f(vu1[i]);
        m = mnew;
    }

#pragma unroll
    for (int off = 8; off <= 32; off <<= 1) {
        float mo = __shfl_xor(m, off, 64);
        float lo = __shfl_xor(l, off, 64);
        float mn = fmaxf(m, mo);
        float s1 = exp2f(m - mn);
        float s2 = exp2f(mo - mn);
        l = l * s1 + lo * s2;
#pragma unroll
        for (int i = 0; i < 8; ++i) {
            float ao = __shfl_xor(a[i], off, 64);
            a[i] = a[i] * s1 + ao * s2;
        }
        m = mn;
    }

    if (g == 0) {
        float inv = 1.f / (l + 1e-16f);
        u16x8 sv = *(const u16x8*)(qbf + (size_t)node * 256 + 192 + h * 8);
        u16x8 o;
#pragma unroll
        for (int i = 0; i < 8; ++i) {
            float t = a[i] * inv + bf2f(sv[i]);
            t = (t > 0.f) ? t : expm1f(t);
            o[i] = f2bf(t);
        }
        *(u16x8*)(h1bf + (size_t)node * 64 + h * 8) = o;
    }
}

// ---------------- fused attention layer 2 (H=1, C=64) + log_softmax ----------------
// One wave per node; 4 groups x 16 lanes; lane owns 4 channels;
// 2 edges per group per iteration; NEXT iteration's indices prefetched.
__global__ __launch_bounds__(256) void attn2(const unsigned short* __restrict__ qbf,
                                             const int* __restrict__ rowptr,
                                             const int* __restrict__ csr_src,
                                             float* __restrict__ out, int N) {
    int node = blockIdx.x * 4 + (threadIdx.x >> 6);
    if (node >= N) return;
    const int lane = threadIdx.x & 63;
    const int g = lane >> 4, j = lane & 15;

    float qx, qy, qz, qw;
    {
        ushort4 qv = *(const ushort4*)(qbf + (size_t)node * 256 + j * 4);
        qx = bf2f(qv.x); qy = bf2f(qv.y); qz = bf2f(qv.z); qw = bf2f(qv.w);
    }
    const float SC = 1.44269504f * 0.125f;                 // log2(e)/sqrt(64)
    float m = NEGBIG, l = 0.f;
    float4 acc = make_float4(0.f, 0.f, 0.f, 0.f);

    const int beg = rowptr[node], end = rowptr[node + 1];
    const int nt = (end - beg + 7) >> 3;

    // prefetch indices for t = 0
    int ni0 = beg + g, ni1 = ni0 + 4;
    bool nv0 = ni0 < end, nv1 = ni1 < end;
    int ns0 = csr_src[nv0 ? ni0 : beg];
    int ns1 = csr_src[nv1 ? ni1 : beg];

    for (int t = 0; t < nt; ++t) {
        bool v0 = nv0, v1 = nv1;
        int s0 = ((unsigned)ns0 < (unsigned)N) ? ns0 : 0;
        int s1 = ((unsigned)ns1 < (unsigned)N) ? ns1 : 0;
        // prefetch indices for t+1
        int i0n = beg + (t + 1) * 8 + g, i1n = i0n + 4;
        nv0 = i0n < end; nv1 = i1n < end;
        ns0 = csr_src[nv0 ? i0n : beg];
        ns1 = csr_src[nv1 ? i1n : beg];

        const unsigned short* kb0 = qbf + (size_t)s0 * 256 + 64 + j * 4;
        const unsigned short* kb1 = qbf + (size_t)s1 * 256 + 64 + j * 4;
        ushort4 ku0 = *(const ushort4*)kb0;
        ushort4 vu0 = *(const ushort4*)(kb0 + 64);
        ushort4 ku1 = *(const ushort4*)kb1;
        ushort4 vu1 = *(const ushort4*)(kb1 + 64);
        float p0 = qx * bf2f(ku0.x) + qy * bf2f(ku0.y)
                 + qz * bf2f(ku0.z) + qw * bf2f(ku0.w);
        float p1 = qx * bf2f(ku1.x) + qy * bf2f(ku1.y)
                 + qz * bf2f(ku1.z) + qw * bf2f(ku1.w);
#pragma unroll
        for (int mask = 1; mask <= 8; mask <<= 1) {
            p0 += __shfl_xor(p0, mask, 64);
            p1 += __shfl_xor(p1, mask, 64);
        }
        float x0 = v0 ? (p0 * SC) : NEGBIG;
        float x1 = v1 ? (p1 * SC) : NEGBIG;
        float mnew = fmaxf(m, fmaxf(x0, x1));
        float corr = exp2f(m - mnew);
        float w0 = v0 ? exp2f(x0 - mnew) : 0.f;
        float w1 = v1 ? exp2f(x1 - mnew) : 0.f;
        l = l * corr + w0 + w1;
        acc.x = acc.x * corr + w0 * bf2f(vu0.x) + w1 * bf2f(vu1.x);
        acc.y = acc.y * corr + w0 * bf2f(vu0.y) + w1 * bf2f(vu1.y);
        acc.z = acc.z * corr + w0 * bf2f(vu0.z) + w1 * bf2f(vu1.z);
        acc.w = acc.w * corr + w0 * bf2f(vu0.w) + w1 * bf2f(vu1.w);
        m = mnew;
    }

#pragma unroll
    for (int off = 16; off <= 32; off <<= 1) {
        float mo = __shfl_xor(m, off, 64);
        float lo = __shfl_xor(l, off, 64);
        float ax = __shfl_xor(acc.x, off, 64);
        float ay = __shfl_xor(acc.y, off, 64);
        float az = __shfl_xor(acc.z, off, 64);
        float aw = __shfl_xor(acc.w, off, 64);
        float mn = fmaxf(m, mo);
        float s1 = exp2f(m - mn);
        float s2 = exp2f(mo - mn);
        l = l * s1 + lo * s2;
        acc.x = acc.x * s1 + ax * s2;
        acc.y = acc.y * s1 + ay * s2;
        acc.z = acc.z * s1 + az * s2;
        acc.w = acc.w * s1 + aw * s2;
        m = mn;
    }

    float inv = 1.f / (l + 1e-16f);
    ushort4 sv = *(const ushort4*)(qbf + (size_t)node * 256 + 192 + j * 4);
    float4 t4;
    t4.x = acc.x * inv + bf2f(sv.x);
    t4.y = acc.y * inv + bf2f(sv.y);
    t4.z = acc.z * inv + bf2f(sv.z);
    t4.w = acc.w * inv + bf2f(sv.w);

    float mx = fmaxf(fmaxf(t4.x, t4.y), fmaxf(t4.z, t4.w));
#pragma unroll
    for (int off = 1; off <= 8; off <<= 1) mx = fmaxf(mx, __shfl_xor(mx, off, 64));
    float es = expf(t4.x - mx) + expf(t4.y - mx) + expf(t4.z - mx) + expf(t4.w - mx);
#pragma unroll
    for (int off = 1; off <= 8; off <<= 1) es += __shfl_xor(es, off, 64);
    float ls = logf(es);
    if (g == 0) {
        float4 o;
        o.x = (t4.x - mx) - ls;
        o.y = (t4.y - mx) - ls;
        o.z = (t4.z - mx) - ls;
        o.w = (t4.w - mx) - ls;
        *(float4*)&out[(size_t)node * 64 + j * 4] = o;
    }
}

// ---------------- launch ----------------
extern "C" void kernel_launch(void* const* d_in, const int* in_sizes, int n_in,
                              void* d_out, int out_size, void* d_ws, size_t ws_size,
                              hipStream_t stream) {
    const int N = in_sizes[0] / 512;
    const int E = in_sizes[1] / 2;
    const float* x   = (const float*)d_in[0];
    const int*   ei  = (const int*)d_in[1];
    const int* src = ei;
    const int* dst = ei + E;
    const float *Wq1 = (const float*)d_in[2],  *bq1 = (const float*)d_in[3];
    const float *Wk1 = (const float*)d_in[4],  *bk1 = (const float*)d_in[5];
    const float *Wv1 = (const float*)d_in[6],  *bv1 = (const float*)d_in[7];
    const float *Ws1 = (const float*)d_in[8],  *bs1 = (const float*)d_in[9];
    const float *Wq2 = (const float*)d_in[10], *bq2 = (const float*)d_in[11];
    const float *Wk2 = (const float*)d_in[12], *bk2 = (const float*)d_in[13];
    const float *Wv2 = (const float*)d_in[14], *bv2 = (const float*)d_in[15];
    const float *Ws2 = (const float*)d_in[16], *bs2 = (const float*)d_in[17];

    auto align16 = [](size_t v) { return (v + 15) & ~(size_t)15; };

    const int nblk = (N + 1023) / 1024;

    float* ws = (float*)d_ws;
    const size_t OFF_QBF  = 0;                                        // N*256 ushort = N*128 f
    const size_t OFF_H1B  = align16(OFF_QBF  + (size_t)N * 128);      // N*64 ushort = N*32 f
    const size_t OFF_BT1  = align16(OFF_H1B  + (size_t)N * 32);       // 65536
    const size_t OFF_BT2  = align16(OFF_BT1  + 65536);                // 8192
    const size_t OFF_BI1  = align16(OFF_BT2  + 8192);                 // 256
    const size_t OFF_BI2  = align16(OFF_BI1  + 256);                  // 256
    const size_t OFF_ROWP = align16(OFF_BI2  + 256);                  // N+1 ints
    const size_t OFF_DEG  = align16(OFF_ROWP + (size_t)N + 1);        // N ints
    const size_t OFF_ROW2 = align16(OFF_DEG  + (size_t)N);            // N ints
    const size_t OFF_CSRC = align16(OFF_ROW2 + (size_t)N);            // E ints
    const size_t OFF_BSUM = align16(OFF_CSRC + (size_t)E);            // nblk ints
    const size_t OFF_BOFF = align16(OFF_BSUM + (size_t)nblk);         // nblk ints
    const size_t TOTAL    = align16(OFF_BOFF + (size_t)nblk);
    if (ws_size < TOTAL * sizeof(float)) return;

    unsigned short* qbf  = (unsigned short*)(ws + OFF_QBF);
    unsigned short* h1bf = (unsigned short*)(ws + OFF_H1B);
    unsigned short* bt1  = (unsigned short*)(ws + OFF_BT1);
    unsigned short* bt2  = (unsigned short*)(ws + OFF_BT2);
    float* bias1 = ws + OFF_BI1;
    float* bias2 = ws + OFF_BI2;
    int* rowptr  = (int*)(ws + OFF_ROWP);
    int* deg     = (int*)(ws + OFF_DEG);
    int* rowptr2 = (int*)(ws + OFF_ROW2);
    int* csr_src = (int*)(ws + OFF_CSRC);
    int* blk_sums = (int*)(ws + OFF_BSUM);
    int* blk_off  = (int*)(ws + OFF_BOFF);
    float* out   = (float*)d_out;

    const int gBlocks = (N + 63) / 64;
    const int nBlocks4 = (N + 3) / 4;
    const int zBlocks = (N + 255) / 256;
    const int histBlocks = (E / 4 + 255) / 256;

    setup_all<<<512 + 64 + zBlocks, 256, 0, stream>>>(
        Wq1, bq1, Wk1, bk1, Wv1, bv1, Ws1, bs1,
        Wq2, bq2, Wk2, bk2, Wv2, bv2, Ws2, bs2,
        bt1, bias1, bt2, bias2, deg, N);

    // ---------- Layer-1 GEMM fused with edge histogram ----------
    gemm1_hist<<<gBlocks + histBlocks, 256, 0, stream>>>(
        x, N, bt1, bias1, qbf, dst, E, N, deg, gBlocks);

    // CSR scan + scatter
    scan_blk_k<<<nblk, 256, 0, stream>>>(deg, N, rowptr, blk_sums);
    scan_top_k<<<1, 64, 0, stream>>>(blk_sums, blk_off, nblk, &rowptr[N]);
    scan_add_k<<<nblk, 256, 0, stream>>>(rowptr, rowptr2, blk_off, N);
    scatter_edges<<<(E + 255) / 256, 256, 0, stream>>>(src, dst, E, N, rowptr2, csr_src);

    // ---------- Layer 1 attention ----------
    attn1<<<nBlocks4, 256, 0, stream>>>(qbf, rowptr, csr_src, h1bf, N);

    // ---------- Layer 2 ----------
    gemm_mfma<1, true><<<gBlocks, 256, 0, stream>>>(h1bf, N, bt2, bias2, qbf);
    attn2<<<nBlocks4, 256, 0, stream>>>(qbf, rowptr, csr_src, out, N);
}

// Round 21
// 217.412 us; speedup vs baseline: 1.0143x; 1.0143x over previous
//
#include <hip/hip_runtime.h>
#include <hip/hip_bf16.h>
#include <math.h>

// Graph transformer: 2x TransformerConv (PyG-style).  FINAL (best config).
// GEMMs in bf16 MFMA (dbuf LDS + reg prefetch) with fragment-major weight
// panel; bf16 table [N][256] = q|k|v|skip. Layer-1 GEMM fused with edge
// histogram (independent work, one launch). Attention fused per-dst-node
// over CSR, group-parallel online softmax, 2 edges/group/iter.
// CSR rowptr via 3-kernel parallel scan; scatter slots via rowptr2 atomics.

typedef __attribute__((ext_vector_type(4))) float f32x4;
typedef __attribute__((ext_vector_type(8))) short bf16x8;
typedef __attribute__((ext_vector_type(8))) unsigned short u16x8;

__device__ inline unsigned short f2bf(float f) {
    union { float f; unsigned u; } v; v.f = f;
    unsigned r = (v.u + 0x7fffu + ((v.u >> 16) & 1u)) >> 16;
    return (unsigned short)r;
}
__device__ inline float bf2f(unsigned short u) {
    union { unsigned u; float f; } v; v.u = ((unsigned)u) << 16; return v.f;
}

#define NEGBIG (-1e30f)

// ---------------- fused setup: both weight panels + deg zero ----------------
__device__ inline void prep_panel(int i, int K,
                                  const float* __restrict__ W0, const float* __restrict__ b0,
                                  const float* __restrict__ W1, const float* __restrict__ b1,
                                  const float* __restrict__ W2, const float* __restrict__ b2,
                                  const float* __restrict__ W3, const float* __restrict__ b3,
                                  unsigned short* __restrict__ Btp, float* __restrict__ bias) {
    int tot = 4 * K * 64;
    if (i < tot) {
        int j    = i & 7;
        int lane = (i >> 3) & 63;
        int ni   = (i >> 9) & 3;
        int kk   = (i >> 11) & 1;
        int w    = (i >> 12) & 3;
        int ks   = i >> 14;
        int ncol = ni * 16 + (lane & 15);
        int k    = ks * 64 + kk * 32 + ((lane >> 4) << 3) + j;
        const float* W = (w == 0) ? W0 : (w == 1) ? W1 : (w == 2) ? W2 : W3;
        Btp[i] = f2bf(W[k * 64 + ncol]);
    }
    if (i < 256) {
        int which = i >> 6;
        const float* b = (which == 0) ? b0 : (which == 1) ? b1 : (which == 2) ? b2 : b3;
        bias[i] = b[i & 63];
    }
}

__global__ void setup_all(const float* __restrict__ Wq1, const float* __restrict__ bq1,
                          const float* __restrict__ Wk1, const float* __restrict__ bk1,
                          const float* __restrict__ Wv1, const float* __restrict__ bv1,
                          const float* __restrict__ Ws1, const float* __restrict__ bs1,
                          const float* __restrict__ Wq2, const float* __restrict__ bq2,
                          const float* __restrict__ Wk2, const float* __restrict__ bk2,
                          const float* __restrict__ Wv2, const float* __restrict__ bv2,
                          const float* __restrict__ Ws2, const float* __restrict__ bs2,
                          unsigned short* __restrict__ bt1, float* __restrict__ bias1,
                          unsigned short* __restrict__ bt2, float* __restrict__ bias2,
                          int* __restrict__ deg, int N) {
    const int b = blockIdx.x;
    const int tid = threadIdx.x;
    if (b < 512) {
        prep_panel(b * 256 + tid, 512, Wq1, bq1, Wk1, bk1, Wv1, bv1, Ws1, bs1, bt1, bias1);
    } else if (b < 512 + 64) {
        prep_panel((b - 512) * 256 + tid, 64, Wq2, bq2, Wk2, bk2, Wv2, bv2, Ws2, bs2, bt2, bias2);
    } else {
        int i = (b - 576) * 256 + tid;
        if (i < N) deg[i] = 0;
    }
}

// ---------------- MFMA GEMM body (device fn): dbuf LDS + reg prefetch ----------------
template<int KSTEPS, bool ABF16>
__device__ void gemm_body(const void* __restrict__ Av, int M,
                          const unsigned short* __restrict__ Bt,
                          const float* __restrict__ bias,
                          unsigned short* __restrict__ outbf, int blk) {
    constexpr int K = KSTEPS * 64;
    __shared__ unsigned short As[2][64][72];
    const int tid = threadIdx.x;
    const int lane = tid & 63;
    const int w = tid >> 6;
    const int node0 = blk * 64;
    const int r16 = lane & 15, g = lane >> 4;

    f32x4 acc[4][4] = {};

    const int srow = tid >> 2;
    const int sc0 = (tid & 3) * 16;
    const int node = node0 + srow;
    const bool nvalid = node < M;

    float4 f0, f1, f2, f3;
    u16x8 a0, a1;

#define ISSUE_LOAD(KS)                                                                     \
    do {                                                                                   \
        if (ABF16) {                                                                       \
            a0 = (u16x8){}; a1 = (u16x8){};                                                \
            if (nvalid) {                                                                  \
                const u16x8* p = (const u16x8*)((const unsigned short*)Av +                \
                                  (size_t)node * K + (KS) * 64 + sc0);                     \
                a0 = p[0]; a1 = p[1];                                                      \
            }                                                                              \
        } else {                                                                           \
            f0 = make_float4(0.f, 0.f, 0.f, 0.f); f1 = f0; f2 = f0; f3 = f0;               \
            if (nvalid) {                                                                  \
                const float4* p = (const float4*)((const float*)Av +                       \
                                   (size_t)node * K + (KS) * 64 + sc0);                    \
                f0 = p[0]; f1 = p[1]; f2 = p[2]; f3 = p[3];                                \
            }                                                                              \
        }                                                                                  \
    } while (0)

#define WRITE_LDS(BUF)                                                                     \
    do {                                                                                   \
        unsigned short t[16];                                                              \
        if (ABF16) {                                                                       \
            _Pragma("unroll")                                                              \
            for (int j = 0; j < 8; ++j) { t[j] = a0[j]; t[8 + j] = a1[j]; }                \
        } else {                                                                           \
            t[0] = f2bf(f0.x); t[1] = f2bf(f0.y); t[2] = f2bf(f0.z); t[3] = f2bf(f0.w);    \
            t[4] = f2bf(f1.x); t[5] = f2bf(f1.y); t[6] = f2bf(f1.z); t[7] = f2bf(f1.w);    \
            t[8] = f2bf(f2.x); t[9] = f2bf(f2.y); t[10] = f2bf(f2.z); t[11] = f2bf(f2.w);  \
            t[12] = f2bf(f3.x); t[13] = f2bf(f3.y); t[14] = f2bf(f3.z); t[15] = f2bf(f3.w);\
        }                                                                                  \
        u16x8 w0, w1;                                                                      \
        _Pragma("unroll")                                                                  \
        for (int j = 0; j < 8; ++j) { w0[j] = t[j]; w1[j] = t[8 + j]; }                    \
        *(u16x8*)&As[BUF][srow][sc0] = w0;                                                 \
        *(u16x8*)&As[BUF][srow][sc0 + 8] = w1;                                             \
    } while (0)

    ISSUE_LOAD(0);
    WRITE_LDS(0);
    __syncthreads();

#pragma unroll
    for (int ks = 0; ks < KSTEPS; ++ks) {
        bf16x8 bfr[8];
#pragma unroll
        for (int kk = 0; kk < 2; ++kk)
#pragma unroll
            for (int ni = 0; ni < 4; ++ni)
                bfr[kk * 4 + ni] = *(const bf16x8*)&Bt[
                    ((size_t)(((ks * 4 + w) * 2 + kk) * 4 + ni) << 9) + (lane << 3)];
        if (ks + 1 < KSTEPS) ISSUE_LOAD(ks + 1);

#pragma unroll
        for (int kk = 0; kk < 2; ++kk) {
            bf16x8 afr[4];
#pragma unroll
            for (int mi = 0; mi < 4; ++mi)
                afr[mi] = *(const bf16x8*)&As[ks & 1][mi * 16 + r16][kk * 32 + g * 8];
#pragma unroll
            for (int ni = 0; ni < 4; ++ni)
#pragma unroll
                for (int mi = 0; mi < 4; ++mi)
                    acc[mi][ni] = __builtin_amdgcn_mfma_f32_16x16x32_bf16(
                        afr[mi], bfr[kk * 4 + ni], acc[mi][ni], 0, 0, 0);
        }

        if (ks + 1 < KSTEPS) WRITE_LDS((ks + 1) & 1);
        __syncthreads();
    }
#undef ISSUE_LOAD
#undef WRITE_LDS

#pragma unroll
    for (int mi = 0; mi < 4; ++mi) {
#pragma unroll
        for (int r = 0; r < 4; ++r) {
            int row = node0 + mi * 16 + g * 4 + r;
            if (row < M) {
                size_t o = (size_t)row * 256 + w * 64;
#pragma unroll
                for (int ni = 0; ni < 4; ++ni)
                    outbf[o + ni * 16 + r16] =
                        f2bf(acc[mi][ni][r] + bias[w * 64 + ni * 16 + r16]);
            }
        }
    }
}

// standalone GEMM kernel (layer 2)
template<int KSTEPS, bool ABF16>
__global__ __launch_bounds__(256) void gemm_mfma(const void* __restrict__ Av, int M,
                                                 const unsigned short* __restrict__ Bt,
                                                 const float* __restrict__ bias,
                                                 unsigned short* __restrict__ outbf) {
    gemm_body<KSTEPS, ABF16>(Av, M, Bt, bias, outbf, blockIdx.x);
}

// layer-1 GEMM fused with edge histogram (independent work, one launch)
__global__ __launch_bounds__(256) void gemm1_hist(const float* __restrict__ x, int M,
                                                  const unsigned short* __restrict__ Bt,
                                                  const float* __restrict__ bias,
                                                  unsigned short* __restrict__ outbf,
                                                  const int* __restrict__ dst, int E, int N,
                                                  int* __restrict__ deg, int gB) {
    if (blockIdx.x < gB) {
        gemm_body<8, false>(x, M, Bt, bias, outbf, blockIdx.x);
    } else {
        int base = ((blockIdx.x - gB) * 256 + threadIdx.x) * 4;
        if (base + 3 < E) {
            int4 d4 = *(const int4*)&dst[base];
            if ((unsigned)d4.x < (unsigned)N) atomicAdd(&deg[d4.x], 1);
            if ((unsigned)d4.y < (unsigned)N) atomicAdd(&deg[d4.y], 1);
            if ((unsigned)d4.z < (unsigned)N) atomicAdd(&deg[d4.z], 1);
            if ((unsigned)d4.w < (unsigned)N) atomicAdd(&deg[d4.w], 1);
        } else {
            for (int i = 0; i < 4; ++i) {
                int e = base + i;
                if (e < E) {
                    int d = dst[e];
                    if ((unsigned)d < (unsigned)N) atomicAdd(&deg[d], 1);
                }
            }
        }
    }
}

// ---------------- CSR scan ----------------
__global__ __launch_bounds__(256) void scan_blk_k(const int* __restrict__ deg, int N,
                                                  int* __restrict__ rowptr,
                                                  int* __restrict__ blk_sums) {
    __shared__ int wsum[4];
    const int t = threadIdx.x;
    const int base = blockIdx.x * 1024 + t * 4;
    int d0 = 0, d1 = 0, d2 = 0, d3 = 0;
    if (base + 3 < N) {
        int4 v = *(const int4*)&deg[base];
        d0 = v.x; d1 = v.y; d2 = v.z; d3 = v.w;
    } else {
        if (base < N)     d0 = deg[base];
        if (base + 1 < N) d1 = deg[base + 1];
        if (base + 2 < N) d2 = deg[base + 2];
    }
    int s = d0 + d1 + d2 + d3;
    int incl = s;
    const int lane = t & 63, w = t >> 6;
#pragma unroll
    for (int off = 1; off < 64; off <<= 1) {
        int v = __shfl_up(incl, off, 64);
        if (lane >= off) incl += v;
    }
    if (lane == 63) wsum[w] = incl;
    __syncthreads();
    int woff = 0;
    if (w > 0) woff += wsum[0];
    if (w > 1) woff += wsum[1];
    if (w > 2) woff += wsum[2];
    int excl = woff + incl - s;
    if (base < N)     rowptr[base]     = excl;
    if (base + 1 < N) rowptr[base + 1] = excl + d0;
    if (base + 2 < N) rowptr[base + 2] = excl + d0 + d1;
    if (base + 3 < N) rowptr[base + 3] = excl + d0 + d1 + d2;
    if (t == 255) blk_sums[blockIdx.x] = woff + incl;
}

__global__ __launch_bounds__(64) void scan_top_k(const int* __restrict__ blk_sums,
                                                 int* __restrict__ blk_off, int nblk,
                                                 int* __restrict__ rowptrN) {
    const int lane = threadIdx.x;
    int carry = 0;
    for (int b = 0; b < nblk; b += 64) {
        int idx = b + lane;
        int v = (idx < nblk) ? blk_sums[idx] : 0;
        int incl = v;
#pragma unroll
        for (int off = 1; off < 64; off <<= 1) {
            int u = __shfl_up(incl, off, 64);
            if (lane >= off) incl += u;
        }
        if (idx < nblk) blk_off[idx] = carry + incl - v;
        carry += __shfl(incl, 63, 64);
    }
    if (lane == 0) *rowptrN = carry;
}

__global__ __launch_bounds__(256) void scan_add_k(int* __restrict__ rowptr,
                                                  int* __restrict__ rowptr2,
                                                  const int* __restrict__ blk_off, int N) {
    const int base = blockIdx.x * 1024 + threadIdx.x * 4;
    const int off = blk_off[blockIdx.x];
    if (base + 3 < N) {
        int4 v = *(int4*)&rowptr[base];
        v.x += off; v.y += off; v.z += off; v.w += off;
        *(int4*)&rowptr[base] = v;
        *(int4*)&rowptr2[base] = v;
    } else {
        for (int i = 0; i < 4; ++i)
            if (base + i < N) {
                int v = rowptr[base + i] + off;
                rowptr[base + i] = v;
                rowptr2[base + i] = v;
            }
    }
}

__global__ void scatter_edges(const int* __restrict__ src, const int* __restrict__ dst,
                              int E, int N,
                              int* __restrict__ rowptr2, int* __restrict__ csr_src) {
    int e = blockIdx.x * 256 + threadIdx.x;
    if (e >= E) return;
    int d = dst[e];
    if ((unsigned)d >= (unsigned)N) return;
    int slot = atomicAdd(&rowptr2[d], 1);
    if ((unsigned)slot < (unsigned)E) csr_src[slot] = src[e];
}

// ---------------- fused attention layer 1 (H=8, C=8) ----------------
// One wave per node; 8 groups x 8 lanes; lane owns head h = lane&7.
// 2 edges per group per iteration (16 in flight).
__global__ __launch_bounds__(256) void attn1(const unsigned short* __restrict__ qbf,
                                             const int* __restrict__ rowptr,
                                             const int* __restrict__ csr_src,
                                             unsigned short* __restrict__ h1bf, int N) {
    int node = blockIdx.x * 4 + (threadIdx.x >> 6);
    if (node >= N) return;
    const int lane = threadIdx.x & 63;
    const int g = lane >> 3, h = lane & 7;

    float q[8];
    {
        u16x8 qv = *(const u16x8*)(qbf + (size_t)node * 256 + h * 8);
#pragma unroll
        for (int i = 0; i < 8; ++i) q[i] = bf2f(qv[i]);
    }

    const float SC = 1.44269504f * 0.35355339059327373f;   // log2(e)/sqrt(8)
    float m = NEGBIG, l = 0.f;
    float a[8] = {};

    const int beg = rowptr[node], end = rowptr[node + 1];
    const int nt = (end - beg + 15) >> 4;

    for (int t = 0; t < nt; ++t) {
        int i0 = beg + t * 16 + g;
        int i1 = i0 + 8;
        bool v0 = i0 < end, v1 = i1 < end;
        int s0 = csr_src[v0 ? i0 : beg];
        int s1 = csr_src[v1 ? i1 : beg];
        s0 = ((unsigned)s0 < (unsigned)N) ? s0 : 0;
        s1 = ((unsigned)s1 < (unsigned)N) ? s1 : 0;
        const unsigned short* kb0 = qbf + (size_t)s0 * 256 + 64 + h * 8;
        const unsigned short* kb1 = qbf + (size_t)s1 * 256 + 64 + h * 8;
        u16x8 ku0 = *(const u16x8*)kb0;
        u16x8 vu0 = *(const u16x8*)(kb0 + 64);
        u16x8 ku1 = *(const u16x8*)kb1;
        u16x8 vu1 = *(const u16x8*)(kb1 + 64);
        float p0 = 0.f, p1 = 0.f;
#pragma unroll
        for (int i = 0; i < 8; ++i) { p0 += q[i] * bf2f(ku0[i]); p1 += q[i] * bf2f(ku1[i]); }
        float x0 = v0 ? (p0 * SC) : NEGBIG;
        float x1 = v1 ? (p1 * SC) : NEGBIG;
        float mnew = fmaxf(m, fmaxf(x0, x1));
        float corr = exp2f(m - mnew);
        float w0 = v0 ? exp2f(x0 - mnew) : 0.f;
        float w1 = v1 ? exp2f(x1 - mnew) : 0.f;
        l = l * corr + w0 + w1;
#pragma unroll
        for (int i = 0; i < 8; ++i)
            a[i] = a[i] * corr + w0 * bf2f(vu0[i]) + w1 * bf2f(vu1[i]);
        m = mnew;
    }

#pragma unroll
    for (int off = 8; off <= 32; off <<= 1) {
        float mo = __shfl_xor(m, off, 64);
        float lo = __shfl_xor(l, off, 64);
        float mn = fmaxf(m, mo);
        float s1 = exp2f(m - mn);
        float s2 = exp2f(mo - mn);
        l = l * s1 + lo * s2;
#pragma unroll
        for (int i = 0; i < 8; ++i) {
            float ao = __shfl_xor(a[i], off, 64);
            a[i] = a[i] * s1 + ao * s2;
        }
        m = mn;
    }

    if (g == 0) {
        float inv = 1.f / (l + 1e-16f);
        u16x8 sv = *(const u16x8*)(qbf + (size_t)node * 256 + 192 + h * 8);
        u16x8 o;
#pragma unroll
        for (int i = 0; i < 8; ++i) {
            float t = a[i] * inv + bf2f(sv[i]);
            t = (t > 0.f) ? t : expm1f(t);
            o[i] = f2bf(t);
        }
        *(u16x8*)(h1bf + (size_t)node * 64 + h * 8) = o;
    }
}

// ---------------- fused attention layer 2 (H=1, C=64) + log_softmax ----------------
// One wave per node; 4 groups x 16 lanes; lane owns 4 channels;
// 2 edges per group per iteration (8 in flight).
__global__ __launch_bounds__(256) void attn2(const unsigned short* __restrict__ qbf,
                                             const int* __restrict__ rowptr,
                                             const int* __restrict__ csr_src,
                                             float* __restrict__ out, int N) {
    int node = blockIdx.x * 4 + (threadIdx.x >> 6);
    if (node >= N) return;
    const int lane = threadIdx.x & 63;
    const int g = lane >> 4, j = lane & 15;

    float qx, qy, qz, qw;
    {
        ushort4 qv = *(const ushort4*)(qbf + (size_t)node * 256 + j * 4);
        qx = bf2f(qv.x); qy = bf2f(qv.y); qz = bf2f(qv.z); qw = bf2f(qv.w);
    }
    const float SC = 1.44269504f * 0.125f;                 // log2(e)/sqrt(64)
    float m = NEGBIG, l = 0.f;
    float4 acc = make_float4(0.f, 0.f, 0.f, 0.f);

    const int beg = rowptr[node], end = rowptr[node + 1];
    const int nt = (end - beg + 7) >> 3;

    for (int t = 0; t < nt; ++t) {
        int i0 = beg + t * 8 + g;
        int i1 = i0 + 4;
        bool v0 = i0 < end, v1 = i1 < end;
        int s0 = csr_src[v0 ? i0 : beg];
        int s1 = csr_src[v1 ? i1 : beg];
        s0 = ((unsigned)s0 < (unsigned)N) ? s0 : 0;
        s1 = ((unsigned)s1 < (unsigned)N) ? s1 : 0;
        const unsigned short* kb0 = qbf + (size_t)s0 * 256 + 64 + j * 4;
        const unsigned short* kb1 = qbf + (size_t)s1 * 256 + 64 + j * 4;
        ushort4 ku0 = *(const ushort4*)kb0;
        ushort4 vu0 = *(const ushort4*)(kb0 + 64);
        ushort4 ku1 = *(const ushort4*)kb1;
        ushort4 vu1 = *(const ushort4*)(kb1 + 64);
        float p0 = qx * bf2f(ku0.x) + qy * bf2f(ku0.y)
                 + qz * bf2f(ku0.z) + qw * bf2f(ku0.w);
        float p1 = qx * bf2f(ku1.x) + qy * bf2f(ku1.y)
                 + qz * bf2f(ku1.z) + qw * bf2f(ku1.w);
#pragma unroll
        for (int mask = 1; mask <= 8; mask <<= 1) {
            p0 += __shfl_xor(p0, mask, 64);
            p1 += __shfl_xor(p1, mask, 64);
        }
        float x0 = v0 ? (p0 * SC) : NEGBIG;
        float x1 = v1 ? (p1 * SC) : NEGBIG;
        float mnew = fmaxf(m, fmaxf(x0, x1));
        float corr = exp2f(m - mnew);
        float w0 = v0 ? exp2f(x0 - mnew) : 0.f;
        float w1 = v1 ? exp2f(x1 - mnew) : 0.f;
        l = l * corr + w0 + w1;
        acc.x = acc.x * corr + w0 * bf2f(vu0.x) + w1 * bf2f(vu1.x);
        acc.y = acc.y * corr + w0 * bf2f(vu0.y) + w1 * bf2f(vu1.y);
        acc.z = acc.z * corr + w0 * bf2f(vu0.z) + w1 * bf2f(vu1.z);
        acc.w = acc.w * corr + w0 * bf2f(vu0.w) + w1 * bf2f(vu1.w);
        m = mnew;
    }

#pragma unroll
    for (int off = 16; off <= 32; off <<= 1) {
        float mo = __shfl_xor(m, off, 64);
        float lo = __shfl_xor(l, off, 64);
        float ax = __shfl_xor(acc.x, off, 64);
        float ay = __shfl_xor(acc.y, off, 64);
        float az = __shfl_xor(acc.z, off, 64);
        float aw = __shfl_xor(acc.w, off, 64);
        float mn = fmaxf(m, mo);
        float s1 = exp2f(m - mn);
        float s2 = exp2f(mo - mn);
        l = l * s1 + lo * s2;
        acc.x = acc.x * s1 + ax * s2;
        acc.y = acc.y * s1 + ay * s2;
        acc.z = acc.z * s1 + az * s2;
        acc.w = acc.w * s1 + aw * s2;
        m = mn;
    }

    float inv = 1.f / (l + 1e-16f);
    ushort4 sv = *(const ushort4*)(qbf + (size_t)node * 256 + 192 + j * 4);
    float4 t4;
    t4.x = acc.x * inv + bf2f(sv.x);
    t4.y = acc.y * inv + bf2f(sv.y);
    t4.z = acc.z * inv + bf2f(sv.z);
    t4.w = acc.w * inv + bf2f(sv.w);

    float mx = fmaxf(fmaxf(t4.x, t4.y), fmaxf(t4.z, t4.w));
#pragma unroll
    for (int off = 1; off <= 8; off <<= 1) mx = fmaxf(mx, __shfl_xor(mx, off, 64));
    float es = expf(t4.x - mx) + expf(t4.y - mx) + expf(t4.z - mx) + expf(t4.w - mx);
#pragma unroll
    for (int off = 1; off <= 8; off <<= 1) es += __shfl_xor(es, off, 64);
    float ls = logf(es);
    if (g == 0) {
        float4 o;
        o.x = (t4.x - mx) - ls;
        o.y = (t4.y - mx) - ls;
        o.z = (t4.z - mx) - ls;
        o.w = (t4.w - mx) - ls;
        *(float4*)&out[(size_t)node * 64 + j * 4] = o;
    }
}

// ---------------- launch ----------------
extern "C" void kernel_launch(void* const* d_in, const int* in_sizes, int n_in,
                              void* d_out, int out_size, void* d_ws, size_t ws_size,
                              hipStream_t stream) {
    const int N = in_sizes[0] / 512;
    const int E = in_sizes[1] / 2;
    const float* x   = (const float*)d_in[0];
    const int*   ei  = (const int*)d_in[1];
    const int* src = ei;
    const int* dst = ei + E;
    const float *Wq1 = (const float*)d_in[2],  *bq1 = (const float*)d_in[3];
    const float *Wk1 = (const float*)d_in[4],  *bk1 = (const float*)d_in[5];
    const float *Wv1 = (const float*)d_in[6],  *bv1 = (const float*)d_in[7];
    const float *Ws1 = (const float*)d_in[8],  *bs1 = (const float*)d_in[9];
    const float *Wq2 = (const float*)d_in[10], *bq2 = (const float*)d_in[11];
    const float *Wk2 = (const float*)d_in[12], *bk2 = (const float*)d_in[13];
    const float *Wv2 = (const float*)d_in[14], *bv2 = (const float*)d_in[15];
    const float *Ws2 = (const float*)d_in[16], *bs2 = (const float*)d_in[17];

    auto align16 = [](size_t v) { return (v + 15) & ~(size_t)15; };

    const int nblk = (N + 1023) / 1024;

    float* ws = (float*)d_ws;
    const size_t OFF_QBF  = 0;                                        // N*256 ushort = N*128 f
    const size_t OFF_H1B  = align16(OFF_QBF  + (size_t)N * 128);      // N*64 ushort = N*32 f
    const size_t OFF_BT1  = align16(OFF_H1B  + (size_t)N * 32);       // 65536
    const size_t OFF_BT2  = align16(OFF_BT1  + 65536);                // 8192
    const size_t OFF_BI1  = align16(OFF_BT2  + 8192);                 // 256
    const size_t OFF_BI2  = align16(OFF_BI1  + 256);                  // 256
    const size_t OFF_ROWP = align16(OFF_BI2  + 256);                  // N+1 ints
    const size_t OFF_DEG  = align16(OFF_ROWP + (size_t)N + 1);        // N ints
    const size_t OFF_ROW2 = align16(OFF_DEG  + (size_t)N);            // N ints
    const size_t OFF_CSRC = align16(OFF_ROW2 + (size_t)N);            // E ints
    const size_t OFF_BSUM = align16(OFF_CSRC + (size_t)E);            // nblk ints
    const size_t OFF_BOFF = align16(OFF_BSUM + (size_t)nblk);         // nblk ints
    const size_t TOTAL    = align16(OFF_BOFF + (size_t)nblk);
    if (ws_size < TOTAL * sizeof(float)) return;

    unsigned short* qbf  = (unsigned short*)(ws + OFF_QBF);
    unsigned short* h1bf = (unsigned short*)(ws + OFF_H1B);
    unsigned short* bt1  = (unsigned short*)(ws + OFF_BT1);
    unsigned short* bt2  = (unsigned short*)(ws + OFF_BT2);
    float* bias1 = ws + OFF_BI1;
    float* bias2 = ws + OFF_BI2;
    int* rowptr  = (int*)(ws + OFF_ROWP);
    int* deg     = (int*)(ws + OFF_DEG);
    int* rowptr2 = (int*)(ws + OFF_ROW2);
    int* csr_src = (int*)(ws + OFF_CSRC);
    int* blk_sums = (int*)(ws + OFF_BSUM);
    int* blk_off  = (int*)(ws + OFF_BOFF);
    float* out   = (float*)d_out;

    const int gBlocks = (N + 63) / 64;
    const int nBlocks4 = (N + 3) / 4;
    const int zBlocks = (N + 255) / 256;
    const int histBlocks = (E / 4 + 255) / 256;

    setup_all<<<512 + 64 + zBlocks, 256, 0, stream>>>(
        Wq1, bq1, Wk1, bk1, Wv1, bv1, Ws1, bs1,
        Wq2, bq2, Wk2, bk2, Wv2, bv2, Ws2, bs2,
        bt1, bias1, bt2, bias2, deg, N);

    // ---------- Layer-1 GEMM fused with edge histogram ----------
    gemm1_hist<<<gBlocks + histBlocks, 256, 0, stream>>>(
        x, N, bt1, bias1, qbf, dst, E, N, deg, gBlocks);

    // CSR scan + scatter
    scan_blk_k<<<nblk, 256, 0, stream>>>(deg, N, rowptr, blk_sums);
    scan_top_k<<<1, 64, 0, stream>>>(blk_sums, blk_off, nblk, &rowptr[N]);
    scan_add_k<<<nblk, 256, 0, stream>>>(rowptr, rowptr2, blk_off, N);
    scatter_edges<<<(E + 255) / 256, 256, 0, stream>>>(src, dst, E, N, rowptr2, csr_src);

    // ---------- Layer 1 attention ----------
    attn1<<<nBlocks4, 256, 0, stream>>>(qbf, rowptr, csr_src, h1bf, N);

    // ---------- Layer 2 ----------
    gemm_mfma<1, true><<<gBlocks, 256, 0, stream>>>(h1bf, N, bt2, bias2, qbf);
    attn2<<<nBlocks4, 256, 0, stream>>>(qbf, rowptr, csr_src, out, N);
}